// Round 12
// baseline (3948.303 us; speedup 1.0000x reference)
//
#include <hip/hip_runtime.h>

// Problem constants: T=1024, B=64, D=256, H=256, 4H=1024, D+H=512.

typedef _Float16 half4_t __attribute__((ext_vector_type(4)));
typedef _Float16 half8_t __attribute__((ext_vector_type(8)));
typedef float floatx4 __attribute__((ext_vector_type(4)));
typedef unsigned uintx4 __attribute__((ext_vector_type(4)));

__device__ __forceinline__ floatx4 mfma16x16x32(half8_t a, half8_t b, floatx4 c) {
#if __has_builtin(__builtin_amdgcn_mfma_f32_16x16x32_f16)
  return __builtin_amdgcn_mfma_f32_16x16x32_f16(a, b, c, 0, 0, 0);
#else
  half4_t alo = __builtin_shufflevector(a, a, 0, 1, 2, 3);
  half4_t ahi = __builtin_shufflevector(a, a, 4, 5, 6, 7);
  half4_t blo = __builtin_shufflevector(b, b, 0, 1, 2, 3);
  half4_t bhi = __builtin_shufflevector(b, b, 4, 5, 6, 7);
  c = __builtin_amdgcn_mfma_f32_16x16x16f16(alo, blo, c, 0, 0, 0);
  c = __builtin_amdgcn_mfma_f32_16x16x16f16(ahi, bhi, c, 0, 0, 0);
  return c;
#endif
}

__device__ __forceinline__ float sigm(float x) { return 1.f / (1.f + __expf(-x)); }
__device__ __forceinline__ float tanh_(float x) {
  float ax = fabsf(x);
  float e = __expf(-2.f * ax);
  float t = (1.f - e) / (1.f + e);
  return x < 0.f ? -t : t;
}

// ---------------------------------------------------------------------------
// K0: W [512][1024] f32 (row-major) -> WT [1024][512] fp16 (col-major of W).
// ---------------------------------------------------------------------------
__global__ __launch_bounds__(256) void k_transpose_w(const float* __restrict__ W,
                                                     _Float16* __restrict__ WT) {
  __shared__ float tile[64][65];
  const int bx = blockIdx.x & 15;
  const int by = blockIdx.x >> 4;
  const int c0 = bx * 64, r0 = by * 64;
  const int tid = threadIdx.x;
#pragma unroll
  for (int i = 0; i < 16; ++i) {
    int idx = tid + i * 256;
    int r = idx >> 6, c = idx & 63;
    tile[r][c] = W[(size_t)(r0 + r) * 1024 + c0 + c];
  }
  __syncthreads();
#pragma unroll
  for (int i = 0; i < 16; ++i) {
    int idx = tid + i * 256;
    int c = idx >> 6, r = idx & 63;
    WT[(size_t)(c0 + c) * 512 + r0 + r] = (_Float16)tile[r][c];
  }
}

// ---------------------------------------------------------------------------
// K1: Gx = X @ W[:256,:] + b, fp16 MFMA, f32 accum, fp16 out. BM=BN=128 BK=32.
// (Passing since R1 -> proves the 16x16x32_f16 A/B/C fragment layouts.)
// ---------------------------------------------------------------------------
__global__ __launch_bounds__(256) void k_gx_gemm(const float* __restrict__ X,
                                                 const _Float16* __restrict__ WT,
                                                 const float* __restrict__ bias,
                                                 _Float16* __restrict__ Gx) {
  const int nb = blockIdx.x & 7;
  const int mb = blockIdx.x >> 3;
  const int m0 = mb * 128, n0 = nb * 128;
  __shared__ __align__(16) _Float16 As[128 * 40];
  __shared__ __align__(16) _Float16 Bs[128 * 40];
  const int tid = threadIdx.x;
  const int wave = tid >> 6, lane = tid & 63;
  const int wm = (wave >> 1) * 64, wn = (wave & 1) * 64;
  const int lm = lane & 15, lg = lane >> 4;
  const int srow = tid >> 1, skh = (tid & 1) * 16;
  floatx4 acc[4][4] = {};
  for (int kt = 0; kt < 256; kt += 32) {
    __syncthreads();
    {
      const float* src = X + (size_t)(m0 + srow) * 256 + kt + skh;
      float4 f0 = ((const float4*)src)[0];
      float4 f1 = ((const float4*)src)[1];
      float4 f2 = ((const float4*)src)[2];
      float4 f3 = ((const float4*)src)[3];
      half8_t h0 = {(_Float16)f0.x, (_Float16)f0.y, (_Float16)f0.z, (_Float16)f0.w,
                    (_Float16)f1.x, (_Float16)f1.y, (_Float16)f1.z, (_Float16)f1.w};
      half8_t h1 = {(_Float16)f2.x, (_Float16)f2.y, (_Float16)f2.z, (_Float16)f2.w,
                    (_Float16)f3.x, (_Float16)f3.y, (_Float16)f3.z, (_Float16)f3.w};
      *(half8_t*)&As[srow * 40 + skh] = h0;
      *(half8_t*)&As[srow * 40 + skh + 8] = h1;
      const _Float16* bsrc = WT + (size_t)(n0 + srow) * 512 + kt + skh;
      half8_t b0 = ((const half8_t*)bsrc)[0];
      half8_t b1 = ((const half8_t*)bsrc)[1];
      *(half8_t*)&Bs[srow * 40 + skh] = b0;
      *(half8_t*)&Bs[srow * 40 + skh + 8] = b1;
    }
    __syncthreads();
    half8_t af[4], bf[4];
#pragma unroll
    for (int mf = 0; mf < 4; ++mf)
      af[mf] = *(const half8_t*)&As[(wm + mf * 16 + lm) * 40 + lg * 8];
#pragma unroll
    for (int nf = 0; nf < 4; ++nf)
      bf[nf] = *(const half8_t*)&Bs[(wn + nf * 16 + lm) * 40 + lg * 8];
#pragma unroll
    for (int mf = 0; mf < 4; ++mf)
#pragma unroll
      for (int nf = 0; nf < 4; ++nf)
        acc[mf][nf] = mfma16x16x32(af[mf], bf[nf], acc[mf][nf]);
  }
#pragma unroll
  for (int mf = 0; mf < 4; ++mf) {
#pragma unroll
    for (int nf = 0; nf < 4; ++nf) {
      const int gm = m0 + wm + mf * 16 + lg * 4;
      const int gn = n0 + wn + nf * 16 + lm;
      const float bv = bias[gn];
#pragma unroll
      for (int i = 0; i < 4; ++i)
        Gx[(size_t)(gm + i) * 1024 + gn] = (_Float16)(acc[mf][nf][i] + bv);
    }
  }
}

// ---------------------------------------------------------------------------
// K1b: pre-swizzle Wh into MFMA B-fragment order.
// WB[((w*8+n)*8+c)*64 + l] = uint4 covering col = w*128+n*16+(l&15),
// k = c*32+(l>>4)*8 .. +7 (fp16 pairs).
// ---------------------------------------------------------------------------
__global__ __launch_bounds__(256) void k_prep_frags(const _Float16* __restrict__ WT,
                                                    uint4* __restrict__ WB) {
  const int gid = blockIdx.x * 256 + threadIdx.x;  // 0..32767
  const int l = gid & 63;
  const int c = (gid >> 6) & 7;
  const int n = (gid >> 9) & 7;
  const int w = gid >> 12;
  const int col = w * 128 + n * 16 + (l & 15);
  const int k0 = c * 32 + (l >> 4) * 8;
  WB[gid] = *(const uint4*)(WT + (size_t)col * 512 + 256 + k0);
}

// ---------------------------------------------------------------------------
// K2: persistent per-batch LSTM recurrence via MFMA. 64 blocks, 512 threads.
//
// R11 post-mortem: asm MFMAs as the LAST writers of acc0..3 -> the hazard
// recognizer can't see inside asm -> no wait-state nops between the MFMA
// VGPR write and the gates ds_write read -> stale acc reads (absmax 3e-2,
// ~= one 32-k chunk).  FIX: chunk 7 of the resident tiles is now an
// INTRINSIC MFMA (compiler inserts hazard nops): AGPR-resident set shrinks
// to chunks 0..6 (112 AGPRs), chunk-7 fragments of tiles 0..3 are streamed
// per step into S3 from the LICM-opaque pointer (loaded at step top -> 7
// chunks of latency cover). Every acc's final writer is intrinsic.
//
// Structure (per wave, per step):
//   chunks 0..6: asm MFMA tiles 0..3 (B direct from AGPR) + intrinsic MFMA
//                tiles 4..7 (B streamed via 3-slot rotation S0..S2)
//   chunk 7:     8 intrinsic MFMAs (tiles 0..3 from S3, tiles 4..7 from S1)
// A-fragment: h row 0 via LDS broadcast; zero region at byte 576 (==64 mod
// 128 -> banks disjoint from h -> conflict-free). Gx/noise prefetched one
// step ahead (R5/R11 pattern).
// ---------------------------------------------------------------------------
#define STREAM_LOAD(SLOT, CH)              \
  SLOT[0] = sb[0 * 512 + (CH) * 64];       \
  SLOT[1] = sb[1 * 512 + (CH) * 64];       \
  SLOT[2] = sb[2 * 512 + (CH) * 64];       \
  SLOT[3] = sb[3 * 512 + (CH) * 64];

#define RES_MFMA(ACC, IDX)                                \
  asm("v_mfma_f32_16x16x32_f16 %0, %1, %2, %0"            \
      : "+v"(ACC)                                         \
      : "v"(af), "a"(rf[IDX]));

#define CHUNK(C, USE, LOADSLOT, DOLOAD)                                  \
  {                                                                      \
    if (DOLOAD) { STREAM_LOAD(LOADSLOT, (C) + 2) }                       \
    half8_t af = *(const half8_t*)(hbase + (C) * 32);                    \
    RES_MFMA(acc0, 7 * 0 + (C))                                          \
    RES_MFMA(acc1, 7 * 1 + (C))                                          \
    RES_MFMA(acc2, 7 * 2 + (C))                                          \
    RES_MFMA(acc3, 7 * 3 + (C))                                          \
    acc4 = mfma16x16x32(af, __builtin_bit_cast(half8_t, USE[0]), acc4);  \
    acc5 = mfma16x16x32(af, __builtin_bit_cast(half8_t, USE[1]), acc5);  \
    acc6 = mfma16x16x32(af, __builtin_bit_cast(half8_t, USE[2]), acc6);  \
    acc7 = mfma16x16x32(af, __builtin_bit_cast(half8_t, USE[3]), acc7);  \
  }

__global__ __attribute__((amdgpu_flat_work_group_size(512, 512),
                          amdgpu_waves_per_eu(2, 2))) void
k_lstm(const _Float16* __restrict__ Gx, const uint4* __restrict__ WB,
       const float* __restrict__ noise, const float* __restrict__ beta_p,
       float* __restrict__ out) {
  __shared__ float gates[1024];                  // 4KB: Wh.h preactivations
  __shared__ __align__(16) _Float16 hxPad[576];  // [0..255]=h; [288..543]=zeros

  const int b = blockIdx.x;
  const int tid = threadIdx.x;
  const int l = tid & 63;
  const int w = tid >> 6;
  const float beta = beta_p[0];

  if (tid < 256) {
    hxPad[tid] = (_Float16)0.f;        // h0 = 0
    hxPad[288 + tid] = (_Float16)0.f;  // zero region (banks disjoint from h)
  }

  // Stage resident B-fragments (tiles 0..3, chunks 0..6) into 112 AGPRs.
  const uintx4* wblp = (const uintx4*)WB + (size_t)w * 4096 + l;
  uintx4 rf[28];
#pragma unroll
  for (int n = 0; n < 4; ++n) {
#pragma unroll
    for (int c = 0; c < 7; ++c) {
      rf[n * 7 + c] = wblp[n * 512 + c * 64];
      asm("" : "+a"(rf[n * 7 + c]));  // force AGPR class; not rematerializable
    }
  }

  // A-fragment base: lanes with (l&15)==0 read h (row 0 of A); all others
  // read the zero region at byte offset 576 (==64 mod 128 -> no bank overlap).
  const _Float16* hbase = hxPad + (((l & 15) == 0) ? 0 : 288) + (l >> 4) * 8;
  const uintx4* sb = wblp + 4 * 512;  // streamed tiles 4..7

  float cx = 0.f, hlast = 0.f;
  __syncthreads();

  // Prefetch step 0's Gx + noise.
  float pg0 = 0.f, pg1 = 0.f, pg2 = 0.f, pg3 = 0.f, pnz = 0.f;
  if (tid < 256) {
    const _Float16* gp = Gx + (size_t)b * 1024 + tid;
    pg0 = (float)gp[0];
    pg1 = (float)gp[256];
    pg2 = (float)gp[512];
    pg3 = (float)gp[768];
    pnz = noise[(size_t)b * 256 + tid];
  }

  for (int t = 0; t < 1024; ++t) {
    const size_t base = (size_t)t * 64 + b;

    // Defeat LICM on streamed weight loads: make sb loop-variant/opaque.
    {
      unsigned lo = (unsigned)(uintptr_t)sb;
      unsigned hi = (unsigned)((uintptr_t)sb >> 32);
      asm volatile("" : "+v"(lo), "+v"(hi));
      sb = (const uintx4*)(((uintptr_t)hi << 32) | lo);
    }

    // Prefetch NEXT step's Gx + noise (consumed at step t+1's pointwise).
    float ng0 = 0.f, ng1 = 0.f, ng2 = 0.f, ng3 = 0.f, nnz = 0.f;
    if (t < 1023 && tid < 256) {
      const _Float16* gp = Gx + (base + 64) * 1024 + tid;
      ng0 = (float)gp[0];
      ng1 = (float)gp[256];
      ng2 = (float)gp[512];
      ng3 = (float)gp[768];
      nnz = noise[(base + 64) * 256 + tid];
    }

    floatx4 acc0 = {0.f, 0.f, 0.f, 0.f}, acc1 = acc0, acc2 = acc0, acc3 = acc0;
    floatx4 acc4 = acc0, acc5 = acc0, acc6 = acc0, acc7 = acc0;

    // Stream prologue: chunks 0,1 of tiles 4..7; chunk 7 of tiles 0..3 (S3,
    // consumed at CHUNK 7 -> ~7 chunks of latency cover). S3 addressed off
    // the opaque sb so LICM cannot hoist it: wblp == sb - 2048.
    uintx4 S0[4], S1[4], S2[4], S3[4];
    STREAM_LOAD(S0, 0)
    STREAM_LOAD(S1, 1)
#pragma unroll
    for (int n = 0; n < 4; ++n) S3[n] = sb[(n - 4) * 512 + 7 * 64];

    CHUNK(0, S0, S2, 1)
    CHUNK(1, S1, S0, 1)
    CHUNK(2, S2, S1, 1)
    CHUNK(3, S0, S2, 1)
    CHUNK(4, S1, S0, 1)
    CHUNK(5, S2, S1, 1)
    CHUNK(6, S0, S2, 0)
    // Chunk 7: ALL-intrinsic MFMAs -> compiler-visible last writers of every
    // acc -> hazard nops before the gates reads are inserted automatically.
    {
      half8_t af = *(const half8_t*)(hbase + 7 * 32);
      acc0 = mfma16x16x32(af, __builtin_bit_cast(half8_t, S3[0]), acc0);
      acc1 = mfma16x16x32(af, __builtin_bit_cast(half8_t, S3[1]), acc1);
      acc2 = mfma16x16x32(af, __builtin_bit_cast(half8_t, S3[2]), acc2);
      acc3 = mfma16x16x32(af, __builtin_bit_cast(half8_t, S3[3]), acc3);
      acc4 = mfma16x16x32(af, __builtin_bit_cast(half8_t, S1[0]), acc4);
      acc5 = mfma16x16x32(af, __builtin_bit_cast(half8_t, S1[1]), acc5);
      acc6 = mfma16x16x32(af, __builtin_bit_cast(half8_t, S1[2]), acc6);
      acc7 = mfma16x16x32(af, __builtin_bit_cast(half8_t, S1[3]), acc7);
    }

    // C row 0 -> gates: lane j<16, reg0 of tile n = col w*128+n*16+j.
    if (l < 16) {
      gates[w * 128 + 0 * 16 + l] = acc0[0];
      gates[w * 128 + 1 * 16 + l] = acc1[0];
      gates[w * 128 + 2 * 16 + l] = acc2[0];
      gates[w * 128 + 3 * 16 + l] = acc3[0];
      gates[w * 128 + 4 * 16 + l] = acc4[0];
      gates[w * 128 + 5 * 16 + l] = acc5[0];
      gates[w * 128 + 6 * 16 + l] = acc6[0];
      gates[w * 128 + 7 * 16 + l] = acc7[0];
    }
    __syncthreads();

    if (tid < 256) {
      float f = sigm(gates[tid] + pg0);
      float ii = sigm(gates[tid + 256] + pg1);
      float gg = tanh_(gates[tid + 512] + pg2);
      float oo = sigm(gates[tid + 768] + pg3);
      cx = f * cx + ii * gg;
      float h = oo * tanh_(cx) + beta * pnz;
      hlast = h;
      out[base * 256 + tid] = h;
      hxPad[tid] = (_Float16)h;  // publish h for step t+1
    }
    pg0 = ng0; pg1 = ng1; pg2 = ng2; pg3 = ng3; pnz = nnz;
    __syncthreads();
  }

  if (tid < 256) {
    out[(size_t)16777216 + (size_t)b * 256 + tid] = hlast;       // final hx
    out[(size_t)16777216 + 16384 + (size_t)b * 256 + tid] = cx;  // final cx
  }
}

// ---------------------------------------------------------------------------
extern "C" void kernel_launch(void* const* d_in, const int* in_sizes, int n_in,
                              void* d_out, int out_size, void* d_ws, size_t ws_size,
                              hipStream_t stream) {
  const float* X = (const float*)d_in[0];      // [1024,64,256]
  const float* W = (const float*)d_in[1];      // [512,1024]
  const float* bias = (const float*)d_in[2];   // [1024]
  const float* beta = (const float*)d_in[3];   // [1]
  const float* noise = (const float*)d_in[4];  // [1024,64,256]
  float* out = (float*)d_out;

  char* ws = (char*)d_ws;
  _Float16* Gx = (_Float16*)ws;                        // 128 MB
  _Float16* WT = (_Float16*)(ws + (size_t)134217728);  // 1 MB
  uint4* WB = (uint4*)(ws + (size_t)135266304);        // 512 KB frag-ordered Wh

  k_transpose_w<<<128, 256, 0, stream>>>(W, WT);
  k_prep_frags<<<128, 256, 0, stream>>>(WT, WB);
  k_gx_gemm<<<4096, 256, 0, stream>>>(X, WT, bias, Gx);
  k_lstm<<<64, 512, 0, stream>>>(Gx, WB, noise, beta, out);
}

// Round 13
// 2370.812 us; speedup vs baseline: 1.6654x; 1.6654x over previous
//
#include <hip/hip_runtime.h>

// Problem constants: T=1024, B=64, D=256, H=256, 4H=1024, D+H=512.

typedef _Float16 half2_t __attribute__((ext_vector_type(2)));
typedef _Float16 half4_t __attribute__((ext_vector_type(4)));
typedef _Float16 half8_t __attribute__((ext_vector_type(8)));
typedef float floatx4 __attribute__((ext_vector_type(4)));

__device__ __forceinline__ float fdot2(unsigned h, unsigned w, float acc) {
#if __has_builtin(__builtin_amdgcn_fdot2)
  return __builtin_amdgcn_fdot2(__builtin_bit_cast(half2_t, h),
                                __builtin_bit_cast(half2_t, w), acc, false);
#else
  half2_t a = __builtin_bit_cast(half2_t, h);
  half2_t b = __builtin_bit_cast(half2_t, w);
  return acc + (float)a[0] * (float)b[0] + (float)a[1] * (float)b[1];
#endif
}

__device__ __forceinline__ floatx4 mfma16x16x32(half8_t a, half8_t b, floatx4 c) {
#if __has_builtin(__builtin_amdgcn_mfma_f32_16x16x32_f16)
  return __builtin_amdgcn_mfma_f32_16x16x32_f16(a, b, c, 0, 0, 0);
#else
  half4_t alo = __builtin_shufflevector(a, a, 0, 1, 2, 3);
  half4_t ahi = __builtin_shufflevector(a, a, 4, 5, 6, 7);
  half4_t blo = __builtin_shufflevector(b, b, 0, 1, 2, 3);
  half4_t bhi = __builtin_shufflevector(b, b, 4, 5, 6, 7);
  c = __builtin_amdgcn_mfma_f32_16x16x16f16(alo, blo, c, 0, 0, 0);
  c = __builtin_amdgcn_mfma_f32_16x16x16f16(ahi, bhi, c, 0, 0, 0);
  return c;
#endif
}

__device__ __forceinline__ float sigm(float x) { return 1.f / (1.f + __expf(-x)); }
__device__ __forceinline__ float tanh_(float x) {
  float ax = fabsf(x);
  float e = __expf(-2.f * ax);
  float t = (1.f - e) / (1.f + e);
  return x < 0.f ? -t : t;
}

// ---------------------------------------------------------------------------
// K0: W [512][1024] f32 (row-major) -> WT [1024][512] fp16 (col-major of W).
// ---------------------------------------------------------------------------
__global__ __launch_bounds__(256) void k_transpose_w(const float* __restrict__ W,
                                                     _Float16* __restrict__ WT) {
  __shared__ float tile[64][65];
  const int bx = blockIdx.x & 15;
  const int by = blockIdx.x >> 4;
  const int c0 = bx * 64, r0 = by * 64;
  const int tid = threadIdx.x;
#pragma unroll
  for (int i = 0; i < 16; ++i) {
    int idx = tid + i * 256;
    int r = idx >> 6, c = idx & 63;
    tile[r][c] = W[(size_t)(r0 + r) * 1024 + c0 + c];
  }
  __syncthreads();
#pragma unroll
  for (int i = 0; i < 16; ++i) {
    int idx = tid + i * 256;
    int c = idx >> 6, r = idx & 63;
    WT[(size_t)(c0 + c) * 512 + r0 + r] = (_Float16)tile[r][c];
  }
}

// ---------------------------------------------------------------------------
// K1: Gx = X @ W[:256,:] + b, fp16 MFMA, f32 accum, fp16 out. BM=BN=128 BK=32.
// ---------------------------------------------------------------------------
__global__ __launch_bounds__(256) void k_gx_gemm(const float* __restrict__ X,
                                                 const _Float16* __restrict__ WT,
                                                 const float* __restrict__ bias,
                                                 _Float16* __restrict__ Gx) {
  const int nb = blockIdx.x & 7;
  const int mb = blockIdx.x >> 3;
  const int m0 = mb * 128, n0 = nb * 128;
  __shared__ __align__(16) _Float16 As[128 * 40];
  __shared__ __align__(16) _Float16 Bs[128 * 40];
  const int tid = threadIdx.x;
  const int wave = tid >> 6, lane = tid & 63;
  const int wm = (wave >> 1) * 64, wn = (wave & 1) * 64;
  const int lm = lane & 15, lg = lane >> 4;
  const int srow = tid >> 1, skh = (tid & 1) * 16;
  floatx4 acc[4][4] = {};
  for (int kt = 0; kt < 256; kt += 32) {
    __syncthreads();
    {
      const float* src = X + (size_t)(m0 + srow) * 256 + kt + skh;
      float4 f0 = ((const float4*)src)[0];
      float4 f1 = ((const float4*)src)[1];
      float4 f2 = ((const float4*)src)[2];
      float4 f3 = ((const float4*)src)[3];
      half8_t h0 = {(_Float16)f0.x, (_Float16)f0.y, (_Float16)f0.z, (_Float16)f0.w,
                    (_Float16)f1.x, (_Float16)f1.y, (_Float16)f1.z, (_Float16)f1.w};
      half8_t h1 = {(_Float16)f2.x, (_Float16)f2.y, (_Float16)f2.z, (_Float16)f2.w,
                    (_Float16)f3.x, (_Float16)f3.y, (_Float16)f3.z, (_Float16)f3.w};
      *(half8_t*)&As[srow * 40 + skh] = h0;
      *(half8_t*)&As[srow * 40 + skh + 8] = h1;
      const _Float16* bsrc = WT + (size_t)(n0 + srow) * 512 + kt + skh;
      half8_t b0 = ((const half8_t*)bsrc)[0];
      half8_t b1 = ((const half8_t*)bsrc)[1];
      *(half8_t*)&Bs[srow * 40 + skh] = b0;
      *(half8_t*)&Bs[srow * 40 + skh + 8] = b1;
    }
    __syncthreads();
    half8_t af[4], bf[4];
#pragma unroll
    for (int mf = 0; mf < 4; ++mf)
      af[mf] = *(const half8_t*)&As[(wm + mf * 16 + lm) * 40 + lg * 8];
#pragma unroll
    for (int nf = 0; nf < 4; ++nf)
      bf[nf] = *(const half8_t*)&Bs[(wn + nf * 16 + lm) * 40 + lg * 8];
#pragma unroll
    for (int mf = 0; mf < 4; ++mf)
#pragma unroll
      for (int nf = 0; nf < 4; ++nf)
        acc[mf][nf] = mfma16x16x32(af[mf], bf[nf], acc[mf][nf]);
  }
#pragma unroll
  for (int mf = 0; mf < 4; ++mf) {
#pragma unroll
    for (int nf = 0; nf < 4; ++nf) {
      const int gm = m0 + wm + mf * 16 + lg * 4;
      const int gn = n0 + wn + nf * 16 + lm;
      const float bv = bias[gn];
#pragma unroll
      for (int i = 0; i < 4; ++i)
        Gx[(size_t)(gm + i) * 1024 + gn] = (_Float16)(acc[mf][nf][i] + bv);
    }
  }
}

// ---------------------------------------------------------------------------
// K2: persistent per-batch LSTM recurrence. 64 blocks (1/CU), 512 threads.
// Thread owns gate columns {tid, tid+512}. Back to the R5 fdot2 structure
// (measured best, 1700us) with its VMEM weight stream removed:
//
// Per column, 32 uint4 chunks of Wh split three ways (budget-exact):
//   chunks 0..6   -> VGPRs (56 dwords/thread; inside the proven 128-v cap;
//                    compiler may re-load some from L2 -- R5-equivalent, OK)
//   chunks 7..22  -> 128 scalar AGPR dwords/thread, "+a"-pinned (R9/R12
//                    proved staging correct). 128a + 128v = 256 = exactly
//                    2 waves/SIMD (R9's 184a+128v=312 was the over-budget
//                    spill). In-loop reads: NON-volatile v_accvgpr_read with
//                    a loop-variant dummy operand -> schedulable (R10's
//                    volatile serialization avoided) but not hoistable (R2's
//                    remat and R8's scratch-spill avoided). VALU->VALU deps
//                    are HW-interlocked: no R11-style hazard exposure.
//   chunks 23..31 -> static LDS wl[1024][9] uint4 = 144KB; 36-dword column
//                    stride -> conflict-free (SQ_LDS_BANK_CONFLICT=0, R3-R8).
// hx in LDS as fp16x2, uniform-address broadcast reads.
// Gx/noise prefetched one step ahead.
// ---------------------------------------------------------------------------
#define RD(dst, src)                          \
  asm("v_accvgpr_read_b32 %0, %1"             \
      : "=v"(dst)                             \
      : "a"(src), "v"(tv));

__global__ __attribute__((amdgpu_flat_work_group_size(512, 512),
                          amdgpu_waves_per_eu(2, 2))) void
k_lstm(const _Float16* __restrict__ Gx, const _Float16* __restrict__ WT,
       const float* __restrict__ noise, const float* __restrict__ beta_p,
       float* __restrict__ out) {
  __shared__ __align__(16) uint4 wl[1024 * 9];  // 144KB weight chunks 23..31
  __shared__ float gates[1024];                 // 4KB
  __shared__ unsigned hx2[128];                 // 512B: 256 fp16 h values

  const int b = blockIdx.x;
  const int tid = threadIdx.x;
  const float beta = beta_p[0];
  const int c0 = tid, c1 = tid + 512;

  // Weight pointers: h-part of the fused matrix (rows 256..511 of WT cols).
  const uint4* p0 = (const uint4*)(WT + (size_t)c0 * 512 + 256);
  const uint4* p1 = (const uint4*)(WT + (size_t)c1 * 512 + 256);

  // Chunks 0..6 -> VGPRs (compiler-managed, R5-equivalent).
  uint4 w0[7], w1[7];
#pragma unroll
  for (int i = 0; i < 7; ++i) w0[i] = p0[i];
#pragma unroll
  for (int i = 0; i < 7; ++i) w1[i] = p1[i];

  // Chunks 7..22 -> 128 scalar AGPR dwords (64 per column).
  const unsigned* q0 = (const unsigned*)(p0 + 7);
  const unsigned* q1 = (const unsigned*)(p1 + 7);
  unsigned ag0[64], ag1[64];
#pragma unroll
  for (int k = 0; k < 64; ++k) {
    ag0[k] = q0[k];
    asm("" : "+a"(ag0[k]));  // pin to AGPR class; not rematerializable
  }
#pragma unroll
  for (int k = 0; k < 64; ++k) {
    ag1[k] = q1[k];
    asm("" : "+a"(ag1[k]));
  }

  // Chunks 23..31 -> LDS.
  uint4* wlp0 = wl + c0 * 9;
  uint4* wlp1 = wl + c1 * 9;
#pragma unroll
  for (int i = 0; i < 9; ++i) wlp0[i] = p0[23 + i];
#pragma unroll
  for (int i = 0; i < 9; ++i) wlp1[i] = p1[23 + i];

  if (tid < 128) hx2[tid] = 0u;
  float cx = 0.f, hlast = 0.f;
  __syncthreads();

  const _Float16* gp0 = Gx + (size_t)b * 1024 + c0;
  const _Float16* gp1 = Gx + (size_t)b * 1024 + c1;
  const float* nzp = noise + (size_t)b * 256 + (tid & 255);
  float* outp = out + (size_t)b * 256 + tid;  // only used when tid<256

  // Prefetch step 0.
  float g0 = (float)gp0[0];
  float g1 = (float)gp1[0];
  float nz = nzp[0];

  for (int t = 0; t < 1024; ++t) {
    int tv = t;  // loop-variant dummy: anchors AGPR reads inside the loop

    // Prefetch step t+1 (hides under the dot-product phase).
    float g0n = 0.f, g1n = 0.f, nzn = 0.f;
    if (t < 1023) {
      g0n = (float)gp0[65536];
      g1n = (float)gp1[65536];
      nzn = nzp[16384];
    }

    float a0e = 0.f, a0o = 0.f, a1e = 0.f, a1o = 0.f;

    // VGPR-resident chunks 0..6 (rows 0..55).
#pragma unroll
    for (int i = 0; i < 7; ++i) {
      uint4 h4 = *(const uint4*)&hx2[i * 4];  // wave-uniform -> LDS broadcast
      a0e = fdot2(h4.x, w0[i].x, a0e);
      a0o = fdot2(h4.y, w0[i].y, a0o);
      a0e = fdot2(h4.z, w0[i].z, a0e);
      a0o = fdot2(h4.w, w0[i].w, a0o);
      a1e = fdot2(h4.x, w1[i].x, a1e);
      a1o = fdot2(h4.y, w1[i].y, a1o);
      a1e = fdot2(h4.z, w1[i].z, a1e);
      a1o = fdot2(h4.w, w1[i].w, a1o);
    }

    // AGPR-resident chunks 7..22 (rows 56..183).
#pragma unroll
    for (int i = 0; i < 16; ++i) {
      uint4 h4 = *(const uint4*)&hx2[(7 + i) * 4];
      unsigned wx, wy, wz, ww;
      RD(wx, ag0[4 * i + 0])
      RD(wy, ag0[4 * i + 1])
      RD(wz, ag0[4 * i + 2])
      RD(ww, ag0[4 * i + 3])
      a0e = fdot2(h4.x, wx, a0e);
      a0o = fdot2(h4.y, wy, a0o);
      a0e = fdot2(h4.z, wz, a0e);
      a0o = fdot2(h4.w, ww, a0o);
      RD(wx, ag1[4 * i + 0])
      RD(wy, ag1[4 * i + 1])
      RD(wz, ag1[4 * i + 2])
      RD(ww, ag1[4 * i + 3])
      a1e = fdot2(h4.x, wx, a1e);
      a1o = fdot2(h4.y, wy, a1o);
      a1e = fdot2(h4.z, wz, a1e);
      a1o = fdot2(h4.w, ww, a1o);
    }

    // LDS-resident chunks 23..31 (rows 184..255).
#pragma unroll
    for (int i = 0; i < 9; ++i) {
      uint4 h4 = *(const uint4*)&hx2[92 + i * 4];
      uint4 wa = wlp0[i];
      uint4 wb = wlp1[i];
      a0e = fdot2(h4.x, wa.x, a0e);
      a0o = fdot2(h4.y, wa.y, a0o);
      a0e = fdot2(h4.z, wa.z, a0e);
      a0o = fdot2(h4.w, wa.w, a0o);
      a1e = fdot2(h4.x, wb.x, a1e);
      a1o = fdot2(h4.y, wb.y, a1o);
      a1e = fdot2(h4.z, wb.z, a1e);
      a1o = fdot2(h4.w, wb.w, a1o);
    }

    gates[c0] = a0e + a0o + g0;
    gates[c1] = a1e + a1o + g1;
    __syncthreads();  // gates ready; all hx2 reads for step t done

    if (tid < 256) {
      float f = sigm(gates[tid]);
      float ii = sigm(gates[tid + 256]);
      float gg = tanh_(gates[tid + 512]);
      float oo = sigm(gates[tid + 768]);
      cx = f * cx + ii * gg;
      float h = oo * tanh_(cx) + beta * nz;
      hlast = h;
      outp[0] = h;
      ((_Float16*)hx2)[tid] = (_Float16)h;  // publish hx for step t+1
    }
    g0 = g0n; g1 = g1n; nz = nzn;
    gp0 += 65536; gp1 += 65536; nzp += 16384; outp += 16384;
    __syncthreads();  // hx2 ready
  }

  if (tid < 256) {
    out[(size_t)16777216 + (size_t)b * 256 + tid] = hlast;       // final hx
    out[(size_t)16777216 + 16384 + (size_t)b * 256 + tid] = cx;  // final cx
  }
}

// ---------------------------------------------------------------------------
extern "C" void kernel_launch(void* const* d_in, const int* in_sizes, int n_in,
                              void* d_out, int out_size, void* d_ws, size_t ws_size,
                              hipStream_t stream) {
  const float* X = (const float*)d_in[0];      // [1024,64,256]
  const float* W = (const float*)d_in[1];      // [512,1024]
  const float* bias = (const float*)d_in[2];   // [1024]
  const float* beta = (const float*)d_in[3];   // [1]
  const float* noise = (const float*)d_in[4];  // [1024,64,256]
  float* out = (float*)d_out;

  char* ws = (char*)d_ws;
  _Float16* Gx = (_Float16*)ws;                        // 128 MB
  _Float16* WT = (_Float16*)(ws + (size_t)134217728);  // 1 MB

  k_transpose_w<<<128, 256, 0, stream>>>(W, WT);
  k_gx_gemm<<<4096, 256, 0, stream>>>(X, WT, bias, Gx);
  k_lstm<<<64, 512, 0, stream>>>(Gx, WT, noise, beta, out);
}